// Round 7
// baseline (764.783 us; speedup 1.0000x reference)
//
#include <hip/hip_runtime.h>
#include <hip/hip_bf16.h>

typedef short short8 __attribute__((ext_vector_type(8)));
typedef float f32x4 __attribute__((ext_vector_type(4)));

#define AS1(p) ((const __attribute__((address_space(1))) void*)(p))
#define AS3(p) ((__attribute__((address_space(3))) void*)(p))

__device__ __forceinline__ ushort f2bf(float f) {
  __hip_bfloat16 h = __float2bfloat16(f);
  return *reinterpret_cast<const ushort*>(&h);
}
__device__ __forceinline__ float bfu2f(ushort u) {
  unsigned int x = ((unsigned int)u) << 16;
  float f;
  __builtin_memcpy(&f, &x, 4);
  return f;
}
__device__ __forceinline__ float silu_f(float v) { return v / (1.f + __expf(-v)); }

// ---------------- LayerNorm fp32-in -> bf16 out (stem, D = NV*1024) --------
template<int NV>
__global__ __launch_bounds__(256) void ln_bf16_k(
    const float* __restrict__ in, const float* __restrict__ sc,
    const float* __restrict__ bi, ushort* __restrict__ out)
{
  const int D = NV * 1024;
  const long row = blockIdx.x;
  const int tx = threadIdx.x;
  const float* p = in + row * (long)D;
  float4 v[NV];
  float s = 0.f, s2 = 0.f;
#pragma unroll
  for (int t = 0; t < NV; ++t) {
    v[t] = *reinterpret_cast<const float4*>(p + t * 1024 + tx * 4);
    s  += v[t].x + v[t].y + v[t].z + v[t].w;
    s2 += v[t].x * v[t].x + v[t].y * v[t].y + v[t].z * v[t].z + v[t].w * v[t].w;
  }
#pragma unroll
  for (int o = 1; o < 64; o <<= 1) { s += __shfl_xor(s, o); s2 += __shfl_xor(s2, o); }
  __shared__ float red[2][4];
  const int wave = tx >> 6;
  if ((tx & 63) == 0) { red[0][wave] = s; red[1][wave] = s2; }
  __syncthreads();
  s  = red[0][0] + red[0][1] + red[0][2] + red[0][3];
  s2 = red[1][0] + red[1][1] + red[1][2] + red[1][3];
  const float mu   = s / D;
  const float rstd = rsqrtf(s2 / D - mu * mu + 1e-6f);
#pragma unroll
  for (int t = 0; t < NV; ++t) {
    const int d = t * 1024 + tx * 4;
    float4 g = *reinterpret_cast<const float4*>(sc + d);
    float4 b = *reinterpret_cast<const float4*>(bi + d);
    ushort4 o;
    o.x = f2bf((v[t].x - mu) * rstd * g.x + b.x);
    o.y = f2bf((v[t].y - mu) * rstd * g.y + b.y);
    o.z = f2bf((v[t].z - mu) * rstd * g.z + b.z);
    o.w = f2bf((v[t].w - mu) * rstd * g.w + b.w);
    *reinterpret_cast<ushort4*>(out + row * (long)D + d) = o;
  }
}

// ---------------- LayerNorm bf16-in -> bf16 out (D = 2048) ------------------
__global__ __launch_bounds__(256) void ln_bf16b_k(
    const ushort* __restrict__ in, const float* __restrict__ sc,
    const float* __restrict__ bi, ushort* __restrict__ out)
{
  const long row = blockIdx.x;
  const int tx = threadIdx.x;
  const int d = tx * 8;
  short8 v8 = *reinterpret_cast<const short8*>(in + row * 2048 + d);
  float v[8];
  float s = 0.f, s2 = 0.f;
#pragma unroll
  for (int j = 0; j < 8; ++j) {
    v[j] = bfu2f((ushort)v8[j]);
    s += v[j]; s2 += v[j] * v[j];
  }
#pragma unroll
  for (int o = 1; o < 64; o <<= 1) { s += __shfl_xor(s, o); s2 += __shfl_xor(s2, o); }
  __shared__ float red[2][4];
  const int wave = tx >> 6;
  if ((tx & 63) == 0) { red[0][wave] = s; red[1][wave] = s2; }
  __syncthreads();
  s  = red[0][0] + red[0][1] + red[0][2] + red[0][3];
  s2 = red[1][0] + red[1][1] + red[1][2] + red[1][3];
  const float mu   = s * (1.f / 2048.f);
  const float rstd = rsqrtf(s2 * (1.f / 2048.f) - mu * mu + 1e-6f);
  float4 g0 = *reinterpret_cast<const float4*>(sc + d);
  float4 g1 = *reinterpret_cast<const float4*>(sc + d + 4);
  float4 b0 = *reinterpret_cast<const float4*>(bi + d);
  float4 b1 = *reinterpret_cast<const float4*>(bi + d + 4);
  const float gg[8] = {g0.x, g0.y, g0.z, g0.w, g1.x, g1.y, g1.z, g1.w};
  const float bb[8] = {b0.x, b0.y, b0.z, b0.w, b1.x, b1.y, b1.z, b1.w};
  short8 o8;
#pragma unroll
  for (int j = 0; j < 8; ++j)
    o8[j] = (short)f2bf((v[j] - mu) * rstd * gg[j] + bb[j]);
  *reinterpret_cast<short8*>(out + row * 2048 + d) = o8;
}

// ---------------- fp32 [K][N] -> bf16 [N][K] (transpose + convert) ----------
__global__ __launch_bounds__(256) void transpose_bf16_k(
    const float* __restrict__ in, ushort* __restrict__ out, int K, int N)
{
  __shared__ float tile[64][65];
  const int k0 = blockIdx.y * 64, n0 = blockIdx.x * 64;
  const int tx = threadIdx.x, ty = threadIdx.y;
#pragma unroll
  for (int r = ty; r < 64; r += 4)
    tile[r][tx] = in[(long)(k0 + r) * N + n0 + tx];
  __syncthreads();
#pragma unroll
  for (int r = ty; r < 64; r += 4)
    out[(long)(n0 + r) * K + k0 + tx] = f2bf(tile[tx][r]);
}

// ============================================================================
// 256x256 GEMM — three schedule VARIANTS for within-run A/B/C ablation.
//   VAR 0: 8-phase WAR-safe (r6 control), counted vmcnt(4)/tile.
//   VAR 1: 2-phase/tile (4 barriers), counted vmcnt(4)/tile.
//   VAR 2: minimal 2-phase: stage full next tile at top, vmcnt(0)+1 barrier.
// Common: 512 thr = 8 waves (2Mx4N), per-wave 128x64, BK=64, LDS 128 KiB,
// XOR swizzle ((row&7)<<4), pre-swizzled global source.
// MODE 0: h=silu(acc+b) bf16; MODE 1: h+=silu(acc+b) bf16; MODE 2: C=acc+b f32.
// ============================================================================
#define STG(gsrc, ldst)                                                          \
  __builtin_amdgcn_global_load_lds(AS1(gsrc),          AS3(ldst),          16, 0, 0); \
  __builtin_amdgcn_global_load_lds(AS1((gsrc) + offQ), AS3((ldst) + 8192), 16, 0, 0)

#define ldsA(B, H) (ldsW + (B) * 65536 + (H) * 16384)
#define ldsB(B, H) (ldsW + (B) * 65536 + 32768 + (H) * 16384)

#define RD_AFG(DST, DB, MH, KS)                                                 \
  _Pragma("unroll") for (int i_ = 0; i_ < 4; ++i_)                              \
    DST[i_] = *(const short8*)(smem + (DB) * 65536 + aOff + ((MH) * 4 + i_) * 2048 + rdk[(KS)])

#define RD_BF(DST, DB, KS)                                                      \
  _Pragma("unroll") for (int j_ = 0; j_ < 4; ++j_)                              \
    DST[j_] = *(const short8*)(smem + (DB) * 65536 + bOff + j_ * 2048 + rdk[(KS)])

#define MFMA16G(AARR, MH, BFR)                                                  \
  _Pragma("unroll") for (int i_ = 0; i_ < 4; ++i_)                              \
  _Pragma("unroll") for (int j_ = 0; j_ < 4; ++j_)                              \
    acc[(MH) * 4 + i_][j_] = __builtin_amdgcn_mfma_f32_16x16x32_bf16(           \
        AARR[i_], BFR[j_], acc[(MH) * 4 + i_][j_], 0, 0, 0)

#define BARRIER __builtin_amdgcn_s_barrier()
#define SP1 __builtin_amdgcn_s_setprio(1)
#define SP0 __builtin_amdgcn_s_setprio(0)
#define LGKM0 do { asm volatile("s_waitcnt lgkmcnt(0)");                        \
                   __builtin_amdgcn_sched_barrier(0); } while (0)
#define W4 do { asm volatile("s_waitcnt vmcnt(4)" ::: "memory");                \
                __builtin_amdgcn_sched_barrier(0); } while (0)
#define W0 do { asm volatile("s_waitcnt vmcnt(0)" ::: "memory");                \
                __builtin_amdgcn_sched_barrier(0); } while (0)
#define WN do {} while (0)

// ---- VAR 0: 8-phase (r6) ----
#define DO_TILE(DB, S1, AO, S2, BO, WAITE)                                      \
  RD_AFG(af, DB, 0, 0);                                                         \
  RD_BF(bf0, DB, 0);                                                            \
  RD_BF(bf1, DB, 1);                                                            \
  if (S1) { STG(aP + (AO), ldsA((DB) ^ 1, 0));                                  \
            STG(aP + (AO) + offH, ldsA((DB) ^ 1, 1)); }                         \
  BARRIER; LGKM0;                                                               \
  SP1; MFMA16G(af, 0, bf0); SP0;                                                \
  BARRIER;                                                                      \
  RD_AFG(af, DB, 1, 0);                                                         \
  if (S2) { STG(bP + (BO), ldsB(DB, 0)); }                                      \
  BARRIER; LGKM0;                                                               \
  SP1; MFMA16G(af, 1, bf0); SP0;                                                \
  BARRIER;                                                                      \
  RD_AFG(af, DB, 0, 1);                                                         \
  if (S2) { STG(bP + (BO) + offH, ldsB(DB, 1)); }                               \
  BARRIER; LGKM0;                                                               \
  SP1; MFMA16G(af, 0, bf1); SP0;                                                \
  BARRIER;                                                                      \
  RD_AFG(af, DB, 1, 1);                                                         \
  BARRIER; LGKM0;                                                               \
  SP1; MFMA16G(af, 1, bf1); SP0;                                                \
  WAITE;                                                                        \
  BARRIER;

// ---- VAR 1: 2-phase/tile, counted vmcnt ----
// P1: read af(mh0,ks0)+ag(mh1,ks0)+bf0+bf1 (16); stage A(t+1); bar|lgkm|32 MFMA|bar
// P2: read af(mh0,ks1)+ag(mh1,ks1) (8); stage B(t+2); bar|lgkm|32 MFMA|vmcnt(4)|bar
#define DO_TILE_B(DB, S1, AO, S2, BO, WAITE)                                    \
  RD_AFG(af, DB, 0, 0);                                                         \
  RD_AFG(ag, DB, 1, 0);                                                         \
  RD_BF(bf0, DB, 0);                                                            \
  RD_BF(bf1, DB, 1);                                                            \
  if (S1) { STG(aP + (AO), ldsA((DB) ^ 1, 0));                                  \
            STG(aP + (AO) + offH, ldsA((DB) ^ 1, 1)); }                         \
  BARRIER; LGKM0;                                                               \
  SP1; MFMA16G(af, 0, bf0); MFMA16G(ag, 1, bf0); SP0;                           \
  BARRIER;                                                                      \
  RD_AFG(af, DB, 0, 1);                                                         \
  RD_AFG(ag, DB, 1, 1);                                                         \
  if (S2) { STG(bP + (BO), ldsB(DB, 0));                                        \
            STG(bP + (BO) + offH, ldsB(DB, 1)); }                               \
  BARRIER; LGKM0;                                                               \
  SP1; MFMA16G(af, 0, bf1); MFMA16G(ag, 1, bf1); SP0;                           \
  WAITE;                                                                        \
  BARRIER;

// ---- VAR 2: minimal 2-phase, vmcnt(0) + 1 barrier per tile ----
#define DO_TILE_D(DB, SG, AO, BO, WAITE)                                        \
  if (SG) { STG(aP + (AO), ldsA((DB) ^ 1, 0));                                  \
            STG(aP + (AO) + offH, ldsA((DB) ^ 1, 1));                           \
            STG(bP + (BO), ldsB((DB) ^ 1, 0));                                  \
            STG(bP + (BO) + offH, ldsB((DB) ^ 1, 1)); }                         \
  RD_AFG(af, DB, 0, 0);                                                         \
  RD_AFG(ag, DB, 0, 1);                                                         \
  RD_BF(bf0, DB, 0);                                                            \
  RD_BF(bf1, DB, 1);                                                            \
  LGKM0;                                                                        \
  SP1; MFMA16G(af, 0, bf0); MFMA16G(ag, 0, bf1); SP0;                           \
  RD_AFG(af, DB, 1, 0);                                                         \
  RD_AFG(ag, DB, 1, 1);                                                         \
  LGKM0;                                                                        \
  SP1; MFMA16G(af, 1, bf0); MFMA16G(ag, 1, bf1); SP0;                           \
  WAITE;                                                                        \
  BARRIER;

template<int MODE, int VAR>
__global__ __launch_bounds__(512, 2) void gemm256_k(
    const ushort* __restrict__ A, const ushort* __restrict__ Bt,
    const float* __restrict__ bias, void* __restrict__ Cv,
    int M, int N, int K)
{
  extern __shared__ char smem[];
  const int tid = threadIdx.x;
  const int lane = tid & 63, wid = tid >> 6;
  const int wr = wid >> 2, wc = wid & 3;
  const int nbx = N >> 8;

  // bijective XCD swizzle (grid % 8 == 0 for all shapes here)
  int bid;
  {
    const int b = blockIdx.x;
    const int cpx = gridDim.x >> 3;
    bid = (b & 7) * cpx + (b >> 3);
  }
  const int bx = bid % nbx, by = bid / nbx;
  const long m0 = (long)by << 8, n0 = (long)bx << 8;

  // staging: thread -> (row tid>>3 [+64], inverse-swizzled 16B chunk)
  const int srow = tid >> 3;
  const int scol = (((tid & 7) * 16) ^ (((tid >> 3) & 7) << 4)) >> 1;  // elements
  const ushort* aP = A  + (m0 + srow) * (long)K + scol;
  const ushort* bP = Bt + (n0 + srow) * (long)K + scol;
  const long offH = 128L * K, offQ = 64L * K;
  char* ldsW = smem + wid * 1024;

  // ds_read offsets (bytes); XOR swizzle ((row&7)<<4) == ((lane&7)<<4)
  int rdk[2];
  rdk[0] = (((lane >> 4) * 16)     ) ^ ((lane & 7) << 4);
  rdk[1] = (((lane >> 4) * 16) + 64) ^ ((lane & 7) << 4);
  const int aOff = wr * 16384 + (lane & 15) * 128;
  const int bOff = 32768 + (wc >> 1) * 16384 + ((wc & 1) * 64 + (lane & 15)) * 128;

  f32x4 acc[8][4] = {};
  const int NT = K >> 6;  // even, >= 4
  short8 af[4], ag[4], bf0[4], bf1[4];

  if constexpr (VAR == 0) {
    STG(aP,      ldsA(0, 0));  STG(aP + offH,      ldsA(0, 1));
    STG(bP,      ldsB(0, 0));  STG(bP + offH,      ldsB(0, 1));
    STG(bP + 64, ldsB(1, 0));  STG(bP + 64 + offH, ldsB(1, 1));
    W4;
    BARRIER;
    for (int t = 0; t < NT - 2; t += 2) {
      DO_TILE(0, 1,  64, 1, 128, W4)
      DO_TILE(1, 1, 128, 1, 192, W4)
      aP += 128; bP += 128;
    }
    DO_TILE(0, 1, 64, 0, 0, W0)
    DO_TILE(1, 0,  0, 0, 0, WN)
  } else if constexpr (VAR == 1) {
    STG(aP,      ldsA(0, 0));  STG(aP + offH,      ldsA(0, 1));
    STG(bP,      ldsB(0, 0));  STG(bP + offH,      ldsB(0, 1));
    STG(bP + 64, ldsB(1, 0));  STG(bP + 64 + offH, ldsB(1, 1));
    W4;
    BARRIER;
    for (int t = 0; t < NT - 2; t += 2) {
      DO_TILE_B(0, 1,  64, 1, 128, W4)
      DO_TILE_B(1, 1, 128, 1, 192, W4)
      aP += 128; bP += 128;
    }
    DO_TILE_B(0, 1, 64, 0, 0, W0)
    DO_TILE_B(1, 0,  0, 0, 0, WN)
  } else {
    STG(aP, ldsA(0, 0));  STG(aP + offH, ldsA(0, 1));
    STG(bP, ldsB(0, 0));  STG(bP + offH, ldsB(0, 1));
    W0;
    BARRIER;
    for (int t = 0; t < NT - 2; t += 2) {
      DO_TILE_D(0, 1,  64,  64, W0)
      DO_TILE_D(1, 1, 128, 128, W0)
      aP += 128; bP += 128;
    }
    DO_TILE_D(0, 1, 64, 64, W0)
    DO_TILE_D(1, 0,  0,  0, WN)
  }

  // epilogue: C/D layout col=lane&15, row=(lane>>4)*4+reg
#pragma unroll
  for (int j = 0; j < 4; ++j) {
    const long col = n0 + wc * 64 + j * 16 + (lane & 15);
    const float bj = bias[col];
#pragma unroll
    for (int i = 0; i < 8; ++i) {
      const long rowb = m0 + wr * 128 + i * 16 + ((lane >> 4) << 2);
#pragma unroll
      for (int r = 0; r < 4; ++r) {
        const float v = acc[i][j][r] + bj;
        const long idx = (rowb + r) * N + col;
        if (MODE == 0) {
          ((ushort*)Cv)[idx] = f2bf(silu_f(v));
        } else if (MODE == 1) {
          ushort* C = (ushort*)Cv;
          C[idx] = f2bf(bfu2f(C[idx]) + silu_f(v));
        } else {
          ((float*)Cv)[idx] = v;
        }
      }
    }
  }
}

// ---------------------------------------------------------------------------
extern "C" void kernel_launch(void* const* d_in, const int* in_sizes, int n_in,
                              void* d_out, int out_size, void* d_ws, size_t ws_size,
                              hipStream_t stream) {
  const float* x     = (const float*)d_in[0];
  const float* ln1_s = (const float*)d_in[1];
  const float* ln1_b = (const float*)d_in[2];
  const float* w1    = (const float*)d_in[3];
  const float* b1    = (const float*)d_in[4];
  const float* bln_s = (const float*)d_in[5];
  const float* bln_b = (const float*)d_in[6];
  const float* bws   = (const float*)d_in[7];
  const float* bbs   = (const float*)d_in[8];
  const float* ln2_s = (const float*)d_in[9];
  const float* ln2_b = (const float*)d_in[10];
  const float* w2    = (const float*)d_in[11];
  const float* b2    = (const float*)d_in[12];
  float* out = (float*)d_out;

  const int M = 8192;
  char* ws = (char*)d_ws;
  ushort* h   = (ushort*)ws;                                  // 8192x2048 bf16
  ushort* Abf = (ushort*)(ws + 33554432);                     // 8192x2048 bf16
  ushort* wt  = (ushort*)(ws + 67108864);                     // bf16 weights^T
  const long W1T = 0;
  const long BLK = 2097152;
  const long W2T = BLK + 6L * 4194304;

  (void)hipFuncSetAttribute((const void*)gemm256_k<0, 0>,
      hipFuncAttributeMaxDynamicSharedMemorySize, 131072);
  (void)hipFuncSetAttribute((const void*)gemm256_k<1, 0>,
      hipFuncAttributeMaxDynamicSharedMemorySize, 131072);
  (void)hipFuncSetAttribute((const void*)gemm256_k<1, 1>,
      hipFuncAttributeMaxDynamicSharedMemorySize, 131072);
  (void)hipFuncSetAttribute((const void*)gemm256_k<1, 2>,
      hipFuncAttributeMaxDynamicSharedMemorySize, 131072);
  (void)hipFuncSetAttribute((const void*)gemm256_k<2, 0>,
      hipFuncAttributeMaxDynamicSharedMemorySize, 131072);

  dim3 tb(64, 4);
  transpose_bf16_k<<<dim3(2048 / 64, 1024 / 64), tb, 0, stream>>>(w1, wt + W1T, 1024, 2048);
  for (int i = 0; i < 6; ++i)
    transpose_bf16_k<<<dim3(32, 32), tb, 0, stream>>>(
        bws + (long)i * 2048 * 2048, wt + BLK + (long)i * 4194304, 2048, 2048);
  transpose_bf16_k<<<dim3(1024 / 64, 2048 / 64), tb, 0, stream>>>(w2, wt + W2T, 2048, 1024);

  // stem: h = silu(LN(x) @ w1 + b1)   (h bf16)
  ln_bf16_k<1><<<M, 256, 0, stream>>>(x, ln1_s, ln1_b, Abf);
  gemm256_k<0, 0><<<32 * 8, 512, 131072, stream>>>(Abf, wt + W1T, b1, (void*)h, M, 2048, 1024);

  // residual blocks: h = h + silu(LN(h) @ w[i] + lb[i])
  // A/B/C ablation: layers 0,1 -> VAR0 (control); 2,3 -> VAR1; 4,5 -> VAR2.
  for (int i = 0; i < 6; ++i) {
    ln_bf16b_k<<<M, 256, 0, stream>>>(h, bln_s + i * 2048, bln_b + i * 2048, Abf);
    const ushort* w = wt + BLK + (long)i * 4194304;
    const float* bb = bbs + i * 2048;
    if (i < 2)
      gemm256_k<1, 0><<<32 * 8, 512, 131072, stream>>>(Abf, w, bb, (void*)h, M, 2048, 2048);
    else if (i < 4)
      gemm256_k<1, 1><<<32 * 8, 512, 131072, stream>>>(Abf, w, bb, (void*)h, M, 2048, 2048);
    else
      gemm256_k<1, 2><<<32 * 8, 512, 131072, stream>>>(Abf, w, bb, (void*)h, M, 2048, 2048);
  }

  // head: out = LN(h) @ w2 + b2
  ln_bf16b_k<<<M, 256, 0, stream>>>(h, ln2_s, ln2_b, Abf);
  gemm256_k<2, 0><<<32 * 4, 512, 131072, stream>>>(Abf, wt + W2T, b2, (void*)out, M, 1024, 2048);
}

// Round 8
// 694.416 us; speedup vs baseline: 1.1013x; 1.1013x over previous
//
#include <hip/hip_runtime.h>
#include <hip/hip_bf16.h>

typedef short short8 __attribute__((ext_vector_type(8)));
typedef float f32x4 __attribute__((ext_vector_type(4)));

#define AS1(p) ((const __attribute__((address_space(1))) void*)(p))
#define AS3(p) ((__attribute__((address_space(3))) void*)(p))

__device__ __forceinline__ ushort f2bf(float f) {
  __hip_bfloat16 h = __float2bfloat16(f);
  return *reinterpret_cast<const ushort*>(&h);
}
__device__ __forceinline__ float bfu2f(ushort u) {
  unsigned int x = ((unsigned int)u) << 16;
  float f;
  __builtin_memcpy(&f, &x, 4);
  return f;
}
__device__ __forceinline__ float silu_f(float v) { return v / (1.f + __expf(-v)); }

// ---------------- LayerNorm fp32-in -> bf16 out (stem only, D = 1024) -------
template<int NV>
__global__ __launch_bounds__(256) void ln_bf16_k(
    const float* __restrict__ in, const float* __restrict__ sc,
    const float* __restrict__ bi, ushort* __restrict__ out)
{
  const int D = NV * 1024;
  const long row = blockIdx.x;
  const int tx = threadIdx.x;
  const float* p = in + row * (long)D;
  float4 v[NV];
  float s = 0.f, s2 = 0.f;
#pragma unroll
  for (int t = 0; t < NV; ++t) {
    v[t] = *reinterpret_cast<const float4*>(p + t * 1024 + tx * 4);
    s  += v[t].x + v[t].y + v[t].z + v[t].w;
    s2 += v[t].x * v[t].x + v[t].y * v[t].y + v[t].z * v[t].z + v[t].w * v[t].w;
  }
#pragma unroll
  for (int o = 1; o < 64; o <<= 1) { s += __shfl_xor(s, o); s2 += __shfl_xor(s2, o); }
  __shared__ float red[2][4];
  const int wave = tx >> 6;
  if ((tx & 63) == 0) { red[0][wave] = s; red[1][wave] = s2; }
  __syncthreads();
  s  = red[0][0] + red[0][1] + red[0][2] + red[0][3];
  s2 = red[1][0] + red[1][1] + red[1][2] + red[1][3];
  const float mu   = s / D;
  const float rstd = rsqrtf(s2 / D - mu * mu + 1e-6f);
#pragma unroll
  for (int t = 0; t < NV; ++t) {
    const int d = t * 1024 + tx * 4;
    float4 g = *reinterpret_cast<const float4*>(sc + d);
    float4 b = *reinterpret_cast<const float4*>(bi + d);
    ushort4 o;
    o.x = f2bf((v[t].x - mu) * rstd * g.x + b.x);
    o.y = f2bf((v[t].y - mu) * rstd * g.y + b.y);
    o.z = f2bf((v[t].z - mu) * rstd * g.z + b.z);
    o.w = f2bf((v[t].w - mu) * rstd * g.w + b.w);
    *reinterpret_cast<ushort4*>(out + row * (long)D + d) = o;
  }
}

// ---------------- row stats: bf16 h (D=2048) -> {mu*rstd, rstd} -------------
__global__ __launch_bounds__(256) void ln_stats_k(
    const ushort* __restrict__ in, float2* __restrict__ stats)
{
  const long row = blockIdx.x;
  const int tx = threadIdx.x;
  short8 v8 = *reinterpret_cast<const short8*>(in + row * 2048 + tx * 8);
  float s = 0.f, s2 = 0.f;
#pragma unroll
  for (int j = 0; j < 8; ++j) {
    const float v = bfu2f((ushort)v8[j]);
    s += v; s2 += v * v;
  }
#pragma unroll
  for (int o = 1; o < 64; o <<= 1) { s += __shfl_xor(s, o); s2 += __shfl_xor(s2, o); }
  __shared__ float red[2][4];
  const int wave = tx >> 6;
  if ((tx & 63) == 0) { red[0][wave] = s; red[1][wave] = s2; }
  __syncthreads();
  if (tx == 0) {
    s  = red[0][0] + red[0][1] + red[0][2] + red[0][3];
    s2 = red[1][0] + red[1][1] + red[1][2] + red[1][3];
    const float mu   = s * (1.f / 2048.f);
    const float rstd = rsqrtf(s2 * (1.f / 2048.f) - mu * mu + 1e-6f);
    stats[row] = make_float2(mu * rstd, rstd);
  }
}

// ---------------- fp32 [K][N] -> bf16 [N][K] (plain, for w1) ----------------
__global__ __launch_bounds__(256) void transpose_bf16_k(
    const float* __restrict__ in, ushort* __restrict__ out, int K, int N)
{
  __shared__ float tile[64][65];
  const int k0 = blockIdx.y * 64, n0 = blockIdx.x * 64;
  const int tx = threadIdx.x, ty = threadIdx.y;
#pragma unroll
  for (int r = ty; r < 64; r += 4)
    tile[r][tx] = in[(long)(k0 + r) * N + n0 + tx];
  __syncthreads();
#pragma unroll
  for (int r = ty; r < 64; r += 4)
    out[(long)(n0 + r) * K + k0 + tx] = f2bf(tile[tx][r]);
}

// ------- fp32 [K][N] -> bf16 [N][K] scaled by g[k]; accumulate u,v ---------
// wt[n,k] = g[k]*W[k,n];  uvw[n] += { sum_k g[k]W[k,n], sum_k beta[k]W[k,n] }
__global__ __launch_bounds__(256) void transpose_scale_k(
    const float* __restrict__ in, const float* __restrict__ g,
    const float* __restrict__ beta, ushort* __restrict__ out,
    float2* __restrict__ uvw, int K, int N)
{
  __shared__ float tile[64][65];
  const int k0 = blockIdx.y * 64, n0 = blockIdx.x * 64;
  const int tx = threadIdx.x, ty = threadIdx.y;
  float pu = 0.f, pv = 0.f;
#pragma unroll
  for (int r = ty; r < 64; r += 4) {
    const float w  = in[(long)(k0 + r) * N + n0 + tx];
    const float ws = g[k0 + r] * w;
    tile[r][tx] = ws;
    pu += ws;
    pv += beta[k0 + r] * w;
  }
  atomicAdd(&uvw[n0 + tx].x, pu);
  atomicAdd(&uvw[n0 + tx].y, pv);
  __syncthreads();
#pragma unroll
  for (int r = ty; r < 64; r += 4)
    out[(long)(n0 + r) * K + k0 + tx] = f2bf(tile[tx][r]);
}

// ============================================================================
// 256x256 GEMM — r6 WAR-safe 8-phase core (verified).  Epilogue modes:
//   MODE 0: C = silu(acc + bias) -> bf16            (stem; LN pre-applied)
//   MODE 3: C = Rin + silu(rstd*acc - mu*rstd*u + v + bias) -> bf16 (block,
//           folded LN; Rin = h_in, C = h_out, no aliasing)
//   MODE 4: C = rstd*acc - mu*rstd*u + v + bias -> f32 (head, folded LN)
// ============================================================================
#define STG(gsrc, ldst)                                                          \
  __builtin_amdgcn_global_load_lds(AS1(gsrc),          AS3(ldst),          16, 0, 0); \
  __builtin_amdgcn_global_load_lds(AS1((gsrc) + offQ), AS3((ldst) + 8192), 16, 0, 0)

#define ldsA(B, H) (ldsW + (B) * 65536 + (H) * 16384)
#define ldsB(B, H) (ldsW + (B) * 65536 + 32768 + (H) * 16384)

#define RD_AF(DB, MH, KS)                                                       \
  _Pragma("unroll") for (int i_ = 0; i_ < 4; ++i_)                              \
    af[i_] = *(const short8*)(smem + (DB) * 65536 + aOff + ((MH) * 4 + i_) * 2048 + rdk[(KS)])

#define RD_BF(DST, DB, KS)                                                      \
  _Pragma("unroll") for (int j_ = 0; j_ < 4; ++j_)                              \
    DST[j_] = *(const short8*)(smem + (DB) * 65536 + bOff + j_ * 2048 + rdk[(KS)])

#define MFMA16(MH, BFR)                                                         \
  _Pragma("unroll") for (int i_ = 0; i_ < 4; ++i_)                              \
  _Pragma("unroll") for (int j_ = 0; j_ < 4; ++j_)                              \
    acc[(MH) * 4 + i_][j_] = __builtin_amdgcn_mfma_f32_16x16x32_bf16(           \
        af[i_], BFR[j_], acc[(MH) * 4 + i_], j_[0] * 0 + acc[(MH) * 4 + i_][j_], 0, 0, 0)

// (note: macro above must stay simple — real one below)
#undef MFMA16
#define MFMA16(MH, BFR)                                                         \
  _Pragma("unroll") for (int i_ = 0; i_ < 4; ++i_)                              \
  _Pragma("unroll") for (int j_ = 0; j_ < 4; ++j_)                              \
    acc[(MH) * 4 + i_][j_] = __builtin_amdgcn_mfma_f32_16x16x32_bf16(           \
        af[i_], BFR[j_], acc[(MH) * 4 + i_][j_], 0, 0, 0)

#define BARRIER __builtin_amdgcn_s_barrier()
#define LGKM0 do { asm volatile("s_waitcnt lgkmcnt(0)");                        \
                   __builtin_amdgcn_sched_barrier(0); } while (0)
#define W4 do { asm volatile("s_waitcnt vmcnt(4)" ::: "memory");                \
                __builtin_amdgcn_sched_barrier(0); } while (0)
#define W0 do { asm volatile("s_waitcnt vmcnt(0)" ::: "memory");                \
                __builtin_amdgcn_sched_barrier(0); } while (0)
#define WN do {} while (0)

#define DO_TILE(DB, S1, AO, S2, BO, WAITE)                                      \
  RD_AF(DB, 0, 0);                                                              \
  RD_BF(bf0, DB, 0);                                                            \
  RD_BF(bf1, DB, 1);                                                            \
  if (S1) { STG(aP + (AO), ldsA((DB) ^ 1, 0));                                  \
            STG(aP + (AO) + offH, ldsA((DB) ^ 1, 1)); }                         \
  BARRIER; LGKM0;                                                               \
  __builtin_amdgcn_s_setprio(1); MFMA16(0, bf0); __builtin_amdgcn_s_setprio(0); \
  BARRIER;                                                                      \
  RD_AF(DB, 1, 0);                                                              \
  if (S2) { STG(bP + (BO), ldsB(DB, 0)); }                                      \
  BARRIER; LGKM0;                                                               \
  __builtin_amdgcn_s_setprio(1); MFMA16(1, bf0); __builtin_amdgcn_s_setprio(0); \
  BARRIER;                                                                      \
  RD_AF(DB, 0, 1);                                                              \
  if (S2) { STG(bP + (BO) + offH, ldsB(DB, 1)); }                               \
  BARRIER; LGKM0;                                                               \
  __builtin_amdgcn_s_setprio(1); MFMA16(0, bf1); __builtin_amdgcn_s_setprio(0); \
  BARRIER;                                                                      \
  RD_AF(DB, 1, 1);                                                              \
  BARRIER; LGKM0;                                                               \
  __builtin_amdgcn_s_setprio(1); MFMA16(1, bf1); __builtin_amdgcn_s_setprio(0); \
  WAITE;                                                                        \
  BARRIER;

template<int MODE>
__global__ __launch_bounds__(512, 2) void gemm256_k(
    const ushort* __restrict__ A, const ushort* __restrict__ Bt,
    const float* __restrict__ bias, const float2* __restrict__ stats,
    const float2* __restrict__ uvw, const ushort* __restrict__ Rin,
    void* __restrict__ Cv, int M, int N, int K)
{
  extern __shared__ char smem[];
  const int tid = threadIdx.x;
  const int lane = tid & 63, wid = tid >> 6;
  const int wr = wid >> 2, wc = wid & 3;
  const int nbx = N >> 8;

  int bid;
  {
    const int b = blockIdx.x;
    const int cpx = gridDim.x >> 3;
    bid = (b & 7) * cpx + (b >> 3);
  }
  const int bx = bid % nbx, by = bid / nbx;
  const long m0 = (long)by << 8, n0 = (long)bx << 8;

  const int srow = tid >> 3;
  const int scol = (((tid & 7) * 16) ^ (((tid >> 3) & 7) << 4)) >> 1;
  const ushort* aP = A  + (m0 + srow) * (long)K + scol;
  const ushort* bP = Bt + (n0 + srow) * (long)K + scol;
  const long offH = 128L * K, offQ = 64L * K;
  char* ldsW = smem + wid * 1024;

  int rdk[2];
  rdk[0] = (((lane >> 4) * 16)     ) ^ ((lane & 7) << 4);
  rdk[1] = (((lane >> 4) * 16) + 64) ^ ((lane & 7) << 4);
  const int aOff = wr * 16384 + (lane & 15) * 128;
  const int bOff = 32768 + (wc >> 1) * 16384 + ((wc & 1) * 64 + (lane & 15)) * 128;

  f32x4 acc[8][4] = {};
  const int NT = K >> 6;

  STG(aP,      ldsA(0, 0));  STG(aP + offH,      ldsA(0, 1));
  STG(bP,      ldsB(0, 0));  STG(bP + offH,      ldsB(0, 1));
  STG(bP + 64, ldsB(1, 0));  STG(bP + 64 + offH, ldsB(1, 1));
  W4;
  BARRIER;

  short8 af[4], bf0[4], bf1[4];
  for (int t = 0; t < NT - 2; t += 2) {
    DO_TILE(0, 1,  64, 1, 128, W4)
    DO_TILE(1, 1, 128, 1, 192, W4)
    aP += 128; bP += 128;
  }
  DO_TILE(0, 1, 64, 0, 0, W0)
  DO_TILE(1, 0,  0, 0, 0, WN)

  // epilogue: C/D layout col=lane&15, row=(lane>>4)*4+reg
  if (MODE == 0) {
#pragma unroll
    for (int j = 0; j < 4; ++j) {
      const long col = n0 + wc * 64 + j * 16 + (lane & 15);
      const float bj = bias[col];
#pragma unroll
      for (int i = 0; i < 8; ++i) {
        const long rowb = m0 + wr * 128 + i * 16 + ((lane >> 4) << 2);
#pragma unroll
        for (int r = 0; r < 4; ++r) {
          const float v = acc[i][j][r] + bj;
          ((ushort*)Cv)[(rowb + r) * N + col] = f2bf(silu_f(v));
        }
      }
    }
  } else {
    float2 uvv[4];
    float  bj4[4];
    long   col4[4];
#pragma unroll
    for (int j = 0; j < 4; ++j) {
      col4[j] = n0 + wc * 64 + j * 16 + (lane & 15);
      uvv[j]  = uvw[col4[j]];
      bj4[j]  = bias[col4[j]];
    }
#pragma unroll
    for (int i = 0; i < 8; ++i) {
      const long rowb = m0 + wr * 128 + i * 16 + ((lane >> 4) << 2);
#pragma unroll
      for (int r = 0; r < 4; ++r) {
        const long row = rowb + r;
        const float2 ms = stats[row];  // {mu*rstd, rstd}
#pragma unroll
        for (int j = 0; j < 4; ++j) {
          const float v = ms.y * acc[i][j][r] - ms.x * uvv[j].x + uvv[j].y + bj4[j];
          const long idx = row * N + col4[j];
          if (MODE == 3) {
            ((ushort*)Cv)[idx] = f2bf(bfu2f(Rin[idx]) + silu_f(v));
          } else {
            ((float*)Cv)[idx] = v;
          }
        }
      }
    }
  }
}

// ---------------------------------------------------------------------------
extern "C" void kernel_launch(void* const* d_in, const int* in_sizes, int n_in,
                              void* d_out, int out_size, void* d_ws, size_t ws_size,
                              hipStream_t stream) {
  const float* x     = (const float*)d_in[0];
  const float* ln1_s = (const float*)d_in[1];
  const float* ln1_b = (const float*)d_in[2];
  const float* w1    = (const float*)d_in[3];
  const float* b1    = (const float*)d_in[4];
  const float* bln_s = (const float*)d_in[5];
  const float* bln_b = (const float*)d_in[6];
  const float* bws   = (const float*)d_in[7];
  const float* bbs   = (const float*)d_in[8];
  const float* ln2_s = (const float*)d_in[9];
  const float* ln2_b = (const float*)d_in[10];
  const float* w2    = (const float*)d_in[11];
  const float* b2    = (const float*)d_in[12];
  float* out = (float*)d_out;

  const int M = 8192;
  char* ws = (char*)d_ws;
  ushort* h0   = (ushort*)ws;                         // 8192x2048 bf16 = 32MB
  ushort* h1   = (ushort*)(ws + 33554432);            // 32MB (aliases stem Abf)
  ushort* Abf  = h1;                                  // stem LN output; dead after stem GEMM
  ushort* wt   = (ushort*)(ws + 67108864);            // bf16 weights^T, 56MB
  float2* uvw  = (float2*)(ws + 125829120);           // 7 x 2048 float2 = 112KB
  float2* stats = (float2*)(ws + 125829120 + 114688); // 8192 float2 = 64KB
  const long W1T = 0;                        // [2048][1024]
  const long BLK = 2097152;                  // 6 x [2048][2048]
  const long W2T = BLK + 6L * 4194304;       // [1024][2048]

  (void)hipFuncSetAttribute((const void*)gemm256_k<0>,
      hipFuncAttributeMaxDynamicSharedMemorySize, 131072);
  (void)hipFuncSetAttribute((const void*)gemm256_k<3>,
      hipFuncAttributeMaxDynamicSharedMemorySize, 131072);
  (void)hipFuncSetAttribute((const void*)gemm256_k<4>,
      hipFuncAttributeMaxDynamicSharedMemorySize, 131072);

  // zero u/v accumulators, then build folded weights
  (void)hipMemsetAsync(uvw, 0, 7 * 2048 * sizeof(float2), stream);

  dim3 tb(64, 4);
  transpose_bf16_k<<<dim3(32, 16), tb, 0, stream>>>(w1, wt + W1T, 1024, 2048);
  for (int i = 0; i < 6; ++i)
    transpose_scale_k<<<dim3(32, 32), tb, 0, stream>>>(
        bws + (long)i * 2048 * 2048, bln_s + i * 2048, bln_b + i * 2048,
        wt + BLK + (long)i * 4194304, uvw + (long)i * 2048, 2048, 2048);
  transpose_scale_k<<<dim3(16, 32), tb, 0, stream>>>(
      w2, ln2_s, ln2_b, wt + W2T, uvw + 6L * 2048, 2048, 1024);

  // stem: h0 = silu(LN(x) @ w1 + b1)
  ln_bf16_k<1><<<M, 256, 0, stream>>>(x, ln1_s, ln1_b, Abf);
  gemm256_k<0><<<32 * 8, 512, 131072, stream>>>(
      Abf, wt + W1T, b1, nullptr, nullptr, nullptr, (void*)h0, M, 2048, 1024);

  // residual blocks (folded LN): h_out = h_in + silu(affine(h_in @ W'))
  ushort* hin = h0;
  ushort* hout = h1;
  for (int i = 0; i < 6; ++i) {
    ln_stats_k<<<M, 256, 0, stream>>>(hin, stats);
    gemm256_k<3><<<32 * 8, 512, 131072, stream>>>(
        hin, wt + BLK + (long)i * 4194304, bbs + i * 2048, stats,
        uvw + (long)i * 2048, hin, (void*)hout, M, 2048, 2048);
    ushort* tmp = hin; hin = hout; hout = tmp;
  }

  // head (folded LN): out = affine(h @ w2') ; hin == h0 after 6 swaps
  ln_stats_k<<<M, 256, 0, stream>>>(hin, stats);
  gemm256_k<4><<<32 * 4, 512, 131072, stream>>>(
      hin, wt + W2T, b2, stats, uvw + 6L * 2048, nullptr, (void*)out, M, 1024, 2048);
}

// Round 9
// 693.135 us; speedup vs baseline: 1.1034x; 1.0018x over previous
//
#include <hip/hip_runtime.h>
#include <hip/hip_bf16.h>

typedef short short8 __attribute__((ext_vector_type(8)));
typedef float f32x4 __attribute__((ext_vector_type(4)));

#define AS1(p) ((const __attribute__((address_space(1))) void*)(p))
#define AS3(p) ((__attribute__((address_space(3))) void*)(p))

__device__ __forceinline__ ushort f2bf(float f) {
  __hip_bfloat16 h = __float2bfloat16(f);
  return *reinterpret_cast<const ushort*>(&h);
}
__device__ __forceinline__ float bfu2f(ushort u) {
  unsigned int x = ((unsigned int)u) << 16;
  float f;
  __builtin_memcpy(&f, &x, 4);
  return f;
}
__device__ __forceinline__ float silu_f(float v) { return v / (1.f + __expf(-v)); }

// ---------------- LayerNorm fp32-in -> bf16 out (stem only, D = 1024) -------
template<int NV>
__global__ __launch_bounds__(256) void ln_bf16_k(
    const float* __restrict__ in, const float* __restrict__ sc,
    const float* __restrict__ bi, ushort* __restrict__ out)
{
  const int D = NV * 1024;
  const long row = blockIdx.x;
  const int tx = threadIdx.x;
  const float* p = in + row * (long)D;
  float4 v[NV];
  float s = 0.f, s2 = 0.f;
#pragma unroll
  for (int t = 0; t < NV; ++t) {
    v[t] = *reinterpret_cast<const float4*>(p + t * 1024 + tx * 4);
    s  += v[t].x + v[t].y + v[t].z + v[t].w;
    s2 += v[t].x * v[t].x + v[t].y * v[t].y + v[t].z * v[t].z + v[t].w * v[t].w;
  }
#pragma unroll
  for (int o = 1; o < 64; o <<= 1) { s += __shfl_xor(s, o); s2 += __shfl_xor(s2, o); }
  __shared__ float red[2][4];
  const int wave = tx >> 6;
  if ((tx & 63) == 0) { red[0][wave] = s; red[1][wave] = s2; }
  __syncthreads();
  s  = red[0][0] + red[0][1] + red[0][2] + red[0][3];
  s2 = red[1][0] + red[1][1] + red[1][2] + red[1][3];
  const float mu   = s / D;
  const float rstd = rsqrtf(s2 / D - mu * mu + 1e-6f);
#pragma unroll
  for (int t = 0; t < NV; ++t) {
    const int d = t * 1024 + tx * 4;
    float4 g = *reinterpret_cast<const float4*>(sc + d);
    float4 b = *reinterpret_cast<const float4*>(bi + d);
    ushort4 o;
    o.x = f2bf((v[t].x - mu) * rstd * g.x + b.x);
    o.y = f2bf((v[t].y - mu) * rstd * g.y + b.y);
    o.z = f2bf((v[t].z - mu) * rstd * g.z + b.z);
    o.w = f2bf((v[t].w - mu) * rstd * g.w + b.w);
    *reinterpret_cast<ushort4*>(out + row * (long)D + d) = o;
  }
}

// ---------------- row stats: bf16 h (D=2048) -> {mu*rstd, rstd} -------------
__global__ __launch_bounds__(256) void ln_stats_k(
    const ushort* __restrict__ in, float2* __restrict__ stats)
{
  const long row = blockIdx.x;
  const int tx = threadIdx.x;
  short8 v8 = *reinterpret_cast<const short8*>(in + row * 2048 + tx * 8);
  float s = 0.f, s2 = 0.f;
#pragma unroll
  for (int j = 0; j < 8; ++j) {
    const float v = bfu2f((ushort)v8[j]);
    s += v; s2 += v * v;
  }
#pragma unroll
  for (int o = 1; o < 64; o <<= 1) { s += __shfl_xor(s, o); s2 += __shfl_xor(s2, o); }
  __shared__ float red[2][4];
  const int wave = tx >> 6;
  if ((tx & 63) == 0) { red[0][wave] = s; red[1][wave] = s2; }
  __syncthreads();
  if (tx == 0) {
    s  = red[0][0] + red[0][1] + red[0][2] + red[0][3];
    s2 = red[1][0] + red[1][1] + red[1][2] + red[1][3];
    const float mu   = s * (1.f / 2048.f);
    const float rstd = rsqrtf(s2 * (1.f / 2048.f) - mu * mu + 1e-6f);
    stats[row] = make_float2(mu * rstd, rstd);
  }
}

// ---------------- fp32 [K][N] -> bf16 [N][K] (plain, for w1) ----------------
__global__ __launch_bounds__(256) void transpose_bf16_k(
    const float* __restrict__ in, ushort* __restrict__ out, int K, int N)
{
  __shared__ float tile[64][65];
  const int k0 = blockIdx.y * 64, n0 = blockIdx.x * 64;
  const int tx = threadIdx.x, ty = threadIdx.y;
#pragma unroll
  for (int r = ty; r < 64; r += 4)
    tile[r][tx] = in[(long)(k0 + r) * N + n0 + tx];
  __syncthreads();
#pragma unroll
  for (int r = ty; r < 64; r += 4)
    out[(long)(n0 + r) * K + k0 + tx] = f2bf(tile[tx][r]);
}

// ------- fp32 [K][N] -> bf16 [N][K] scaled by g[k]; accumulate u,v ---------
__global__ __launch_bounds__(256) void transpose_scale_k(
    const float* __restrict__ in, const float* __restrict__ g,
    const float* __restrict__ beta, ushort* __restrict__ out,
    float2* __restrict__ uvw, int K, int N)
{
  __shared__ float tile[64][65];
  const int k0 = blockIdx.y * 64, n0 = blockIdx.x * 64;
  const int tx = threadIdx.x, ty = threadIdx.y;
  float pu = 0.f, pv = 0.f;
#pragma unroll
  for (int r = ty; r < 64; r += 4) {
    const float w  = in[(long)(k0 + r) * N + n0 + tx];
    const float ws = g[k0 + r] * w;
    tile[r][tx] = ws;
    pu += ws;
    pv += beta[k0 + r] * w;
  }
  atomicAdd(&uvw[n0 + tx].x, pu);
  atomicAdd(&uvw[n0 + tx].y, pv);
  __syncthreads();
#pragma unroll
  for (int r = ty; r < 64; r += 4)
    out[(long)(n0 + r) * K + k0 + tx] = f2bf(tile[tx][r]);
}

// ============================================================================
// 256x256 GEMM — pipelined K-loop: ds_reads for phase k+1 issue during MFMA
// of phase k (counted lgkmcnt, alternating afx/afy frag sets, bf re-filled
// mid-tile). 2 barriers/tile. WAR ledger:
//   - A(t+1) staged P1 -> ldsA(p^1): its reads drained at P4(t-1) lgkm0 + bar.
//   - B(t+2) staged P4 -> ldsB(p): all waves' bf reads done by P3 wait + bar.
//   - vmcnt(4) at P4 keeps only B(t+2) in flight; A(t+1),B(t+1) landed.
// MODE 0: silu(acc+b)->bf16 | MODE 3: Rin+silu(affine)->bf16 | MODE 4: f32.
// ============================================================================
#define STG(gsrc, ldst)                                                          \
  __builtin_amdgcn_global_load_lds(AS1(gsrc),          AS3(ldst),          16, 0, 0); \
  __builtin_amdgcn_global_load_lds(AS1((gsrc) + offQ), AS3((ldst) + 8192), 16, 0, 0)

#define ldsA(B, H) (ldsW + (B) * 65536 + (H) * 16384)
#define ldsB(B, H) (ldsW + (B) * 65536 + 32768 + (H) * 16384)

#define RD_AF(DST, DB, MH, KS)                                                  \
  _Pragma("unroll") for (int i_ = 0; i_ < 4; ++i_)                              \
    DST[i_] = *(const short8*)(smem + (DB) * 65536 + aOff + ((MH) * 4 + i_) * 2048 + rdk[(KS)])

#define RD_BF(DST, DB, KS)                                                      \
  _Pragma("unroll") for (int j_ = 0; j_ < 4; ++j_)                              \
    DST[j_] = *(const short8*)(smem + (DB) * 65536 + bOff + j_ * 2048 + rdk[(KS)])

#define MFMA16(AREG, MH, BREG)                                                  \
  _Pragma("unroll") for (int i_ = 0; i_ < 4; ++i_)                              \
  _Pragma("unroll") for (int j_ = 0; j_ < 4; ++j_)                              \
    acc[(MH) * 4 + i_][j_] = __builtin_amdgcn_mfma_f32_16x16x32_bf16(           \
        AREG[i_], BREG[j_], acc[(MH) * 4 + i_][j_], 0, 0, 0)

#define BARRIER __builtin_amdgcn_s_barrier()
#define SP1 __builtin_amdgcn_s_setprio(1)
#define SP0 __builtin_amdgcn_s_setprio(0)
#define SBAR __builtin_amdgcn_sched_barrier(0)
#define LGKMW(N) do { asm volatile("s_waitcnt lgkmcnt(" #N ")"); SBAR; } while (0)
#define W4 do { asm volatile("s_waitcnt vmcnt(4)" ::: "memory"); SBAR; } while (0)
#define W0 do { asm volatile("s_waitcnt vmcnt(0)" ::: "memory"); SBAR; } while (0)
#define WN do {} while (0)

// One K-tile, 4 MFMA clusters, reads pipelined one cluster ahead.
#define DO_TILE(DB, S1, AO, S2, BO, WAITE)                                      \
  /* P1: issue afx(ks0), bf(ks0), afy(ks0-next-half); stage A(t+1) */           \
  RD_AF(afx, DB, 0, 0);                                                         \
  RD_BF(bf, DB, 0);                                                             \
  RD_AF(afy, DB, 1, 0);                                                         \
  if (S1) { STG(aP + (AO), ldsA((DB) ^ 1, 0));                                  \
            STG(aP + (AO) + offH, ldsA((DB) ^ 1, 1)); }                         \
  LGKMW(4);                                    /* afx+bf done; afy in flight */ \
  SP1; MFMA16(afx, 0, bf); SP0;                                                 \
  /* P2: issue afx(ks1) under MFMA(afy); then re-fill bf(ks1) */                \
  RD_AF(afx, DB, 0, 1);                                                         \
  LGKMW(4);                                    /* afy done; afx in flight   */  \
  SP1; MFMA16(afy, 1, bf); SP0;                                                 \
  RD_BF(bf, DB, 1);                                                             \
  SBAR;                                                                         \
  /* P3: issue afy(ks1) under MFMA(afx,bf-ks1) */                               \
  RD_AF(afy, DB, 1, 1);                                                         \
  LGKMW(4);                                    /* afx+bf done; afy in flight */ \
  SP1; MFMA16(afx, 0, bf); SP0;                                                 \
  BARRIER;                                     /* all B(p) reads complete */    \
  /* P4: stage B(t+2) into ldsB(p); final MFMA; counted vmcnt */                \
  if (S2) { STG(bP + (BO), ldsB(DB, 0));                                        \
            STG(bP + (BO) + offH, ldsB(DB, 1)); }                               \
  LGKMW(0);                                                                     \
  SP1; MFMA16(afy, 1, bf); SP0;                                                 \
  WAITE;                                                                        \
  BARRIER;

template<int MODE>
__global__ __launch_bounds__(512, 2) void gemm256_k(
    const ushort* __restrict__ A, const ushort* __restrict__ Bt,
    const float* __restrict__ bias, const float2* __restrict__ stats,
    const float2* __restrict__ uvw, const ushort* __restrict__ Rin,
    void* __restrict__ Cv, int M, int N, int K)
{
  extern __shared__ char smem[];
  const int tid = threadIdx.x;
  const int lane = tid & 63, wid = tid >> 6;
  const int wr = wid >> 2, wc = wid & 3;
  const int nbx = N >> 8;

  int bid;
  {
    const int b = blockIdx.x;
    const int cpx = gridDim.x >> 3;
    bid = (b & 7) * cpx + (b >> 3);
  }
  const int bx = bid % nbx, by = bid / nbx;
  const long m0 = (long)by << 8, n0 = (long)bx << 8;

  const int srow = tid >> 3;
  const int scol = (((tid & 7) * 16) ^ (((tid >> 3) & 7) << 4)) >> 1;
  const ushort* aP = A  + (m0 + srow) * (long)K + scol;
  const ushort* bP = Bt + (n0 + srow) * (long)K + scol;
  const long offH = 128L * K, offQ = 64L * K;
  char* ldsW = smem + wid * 1024;

  int rdk[2];
  rdk[0] = (((lane >> 4) * 16)     ) ^ ((lane & 7) << 4);
  rdk[1] = (((lane >> 4) * 16) + 64) ^ ((lane & 7) << 4);
  const int aOff = wr * 16384 + (lane & 15) * 128;
  const int bOff = 32768 + (wc >> 1) * 16384 + ((wc & 1) * 64 + (lane & 15)) * 128;

  f32x4 acc[8][4] = {};
  const int NT = K >> 6;  // even, >= 4

  // prologue: A(0), B(0), B(1); keep B(1) in flight
  STG(aP,      ldsA(0, 0));  STG(aP + offH,      ldsA(0, 1));
  STG(bP,      ldsB(0, 0));  STG(bP + offH,      ldsB(0, 1));
  STG(bP + 64, ldsB(1, 0));  STG(bP + 64 + offH, ldsB(1, 1));
  W4;
  BARRIER;

  short8 afx[4], afy[4], bf[4];
  for (int t = 0; t < NT - 2; t += 2) {
    DO_TILE(0, 1,  64, 1, 128, W4)
    DO_TILE(1, 1, 128, 1, 192, W4)
    aP += 128; bP += 128;
  }
  // tail pair: stage only A(NT-1); drain all at NT-2 P4.
  DO_TILE(0, 1, 64, 0, 0, W0)
  DO_TILE(1, 0,  0, 0, 0, WN)

  // epilogue: C/D layout col=lane&15, row=(lane>>4)*4+reg
  if (MODE == 0) {
#pragma unroll
    for (int j = 0; j < 4; ++j) {
      const long col = n0 + wc * 64 + j * 16 + (lane & 15);
      const float bj = bias[col];
#pragma unroll
      for (int i = 0; i < 8; ++i) {
        const long rowb = m0 + wr * 128 + i * 16 + ((lane >> 4) << 2);
#pragma unroll
        for (int r = 0; r < 4; ++r) {
          const float v = acc[i][j][r] + bj;
          ((ushort*)Cv)[(rowb + r) * N + col] = f2bf(silu_f(v));
        }
      }
    }
  } else {
    float2 uvv[4];
    float  bj4[4];
    long   col4[4];
#pragma unroll
    for (int j = 0; j < 4; ++j) {
      col4[j] = n0 + wc * 64 + j * 16 + (lane & 15);
      uvv[j]  = uvw[col4[j]];
      bj4[j]  = bias[col4[j]];
    }
#pragma unroll
    for (int i = 0; i < 8; ++i) {
      const long rowb = m0 + wr * 128 + i * 16 + ((lane >> 4) << 2);
#pragma unroll
      for (int r = 0; r < 4; ++r) {
        const long row = rowb + r;
        const float2 ms = stats[row];  // {mu*rstd, rstd}
#pragma unroll
        for (int j = 0; j < 4; ++j) {
          const float v = ms.y * acc[i][j][r] - ms.x * uvv[j].x + uvv[j].y + bj4[j];
          const long idx = row * N + col4[j];
          if (MODE == 3) {
            ((ushort*)Cv)[idx] = f2bf(bfu2f(Rin[idx]) + silu_f(v));
          } else {
            ((float*)Cv)[idx] = v;
          }
        }
      }
    }
  }
}

// ---------------------------------------------------------------------------
extern "C" void kernel_launch(void* const* d_in, const int* in_sizes, int n_in,
                              void* d_out, int out_size, void* d_ws, size_t ws_size,
                              hipStream_t stream) {
  const float* x     = (const float*)d_in[0];
  const float* ln1_s = (const float*)d_in[1];
  const float* ln1_b = (const float*)d_in[2];
  const float* w1    = (const float*)d_in[3];
  const float* b1    = (const float*)d_in[4];
  const float* bln_s = (const float*)d_in[5];
  const float* bln_b = (const float*)d_in[6];
  const float* bws   = (const float*)d_in[7];
  const float* bbs   = (const float*)d_in[8];
  const float* ln2_s = (const float*)d_in[9];
  const float* ln2_b = (const float*)d_in[10];
  const float* w2    = (const float*)d_in[11];
  const float* b2    = (const float*)d_in[12];
  float* out = (float*)d_out;

  const int M = 8192;
  char* ws = (char*)d_ws;
  ushort* h0   = (ushort*)ws;                         // 8192x2048 bf16 = 32MB
  ushort* h1   = (ushort*)(ws + 33554432);            // 32MB (aliases stem Abf)
  ushort* Abf  = h1;
  ushort* wt   = (ushort*)(ws + 67108864);            // bf16 weights^T, 56MB
  float2* uvw  = (float2*)(ws + 125829120);           // 7 x 2048 float2
  float2* stats = (float2*)(ws + 125829120 + 114688); // 8192 float2
  const long W1T = 0;
  const long BLK = 2097152;
  const long W2T = BLK + 6L * 4194304;

  (void)hipFuncSetAttribute((const void*)gemm256_k<0>,
      hipFuncAttributeMaxDynamicSharedMemorySize, 131072);
  (void)hipFuncSetAttribute((const void*)gemm256_k<3>,
      hipFuncAttributeMaxDynamicSharedMemorySize, 131072);
  (void)hipFuncSetAttribute((const void*)gemm256_k<4>,
      hipFuncAttributeMaxDynamicSharedMemorySize, 131072);

  (void)hipMemsetAsync(uvw, 0, 7 * 2048 * sizeof(float2), stream);

  dim3 tb(64, 4);
  transpose_bf16_k<<<dim3(32, 16), tb, 0, stream>>>(w1, wt + W1T, 1024, 2048);
  for (int i = 0; i < 6; ++i)
    transpose_scale_k<<<dim3(32, 32), tb, 0, stream>>>(
        bws + (long)i * 2048 * 2048, bln_s + i * 2048, bln_b + i * 2048,
        wt + BLK + (long)i * 4194304, uvw + (long)i * 2048, 2048, 2048);
  transpose_scale_k<<<dim3(16, 32), tb, 0, stream>>>(
      w2, ln2_s, ln2_b, wt + W2T, uvw + 6L * 2048, 2048, 1024);

  // stem: h0 = silu(LN(x) @ w1 + b1)
  ln_bf16_k<1><<<M, 256, 0, stream>>>(x, ln1_s, ln1_b, Abf);
  gemm256_k<0><<<32 * 8, 512, 131072, stream>>>(
      Abf, wt + W1T, b1, nullptr, nullptr, nullptr, (void*)h0, M, 2048, 1024);

  // residual blocks (folded LN): h_out = h_in + silu(affine(h_in @ W'))
  ushort* hin = h0;
  ushort* hout = h1;
  for (int i = 0; i < 6; ++i) {
    ln_stats_k<<<M, 256, 0, stream>>>(hin, stats);
    gemm256_k<3><<<32 * 8, 512, 131072, stream>>>(
        hin, wt + BLK + (long)i * 4194304, bbs + i * 2048, stats,
        uvw + (long)i * 2048, hin, (void*)hout, M, 2048, 2048);
    ushort* tmp = hin; hin = hout; hout = tmp;
  }

  // head (folded LN): out = affine(h @ w2')
  ln_stats_k<<<M, 256, 0, stream>>>(hin, stats);
  gemm256_k<4><<<32 * 4, 512, 131072, stream>>>(
      hin, wt + W2T, b2, stats, uvw + 6L * 2048, nullptr, (void*)out, M, 1024, 2048);
}